// Round 1
// baseline (48.520 us; speedup 1.0000x reference)
//
#include <hip/hip_runtime.h>
#include <hip/hip_bf16.h>

typedef float f32x4 __attribute__((ext_vector_type(4)));
typedef short short8 __attribute__((ext_vector_type(8)));

constexpr int TOKENS = 16;
constexpr int IN_F   = 4096;
constexpr int OUT_F  = 11008;
constexpr int WAVES  = 4;              // K-split: one segment per wave
constexpr int SEG_K  = IN_F / WAVES;   // 1024
constexpr int NTILES = OUT_F / 16;     // 688 output tiles

// f32 -> bf16, round-to-nearest-even
__device__ __forceinline__ short bf16_rne(float f) {
    unsigned u = __builtin_bit_cast(unsigned, f);
    u += 0x7fffu + ((u >> 16) & 1u);
    return (short)(u >> 16);
}
// int (0..126) -> bf16 is exact: truncation == RNE
__device__ __forceinline__ short bf16_from_int(int v) {
    float f = (float)v;
    return (short)(__builtin_bit_cast(unsigned, f) >> 16);
}

__global__ __launch_bounds__(256) void Int8Linear_kernel(
    const float* __restrict__ x,      // [16][4096] f32
    const int*   __restrict__ w,      // [11008][4096] int32 (0..126)
    const float* __restrict__ scale,  // [11008]
    const float* __restrict__ bias,   // [11008]
    float*       __restrict__ out)    // [16][11008] f32
{
    const int tid  = threadIdx.x;
    const int wave = tid >> 6;        // 0..3  -> K segment
    const int lane = tid & 63;
    const int m    = lane & 15;       // A row (token) and B col (output within tile)
    const int g    = lane >> 4;       // k-group (0..3), 8 elems each
    const int n0   = blockIdx.x * 16; // output tile base

    const float* xp = x + (size_t)m * IN_F + wave * SEG_K + g * 8;
    const int*   wp = w + (size_t)(n0 + m) * IN_F + wave * SEG_K + g * 8;

    f32x4 acc = {0.f, 0.f, 0.f, 0.f};

    #pragma unroll 4
    for (int kb = 0; kb < SEG_K / 32; ++kb) {
        float4 xa = *(const float4*)xp;
        float4 xb = *(const float4*)(xp + 4);
        int4   wa = *(const int4*)wp;
        int4   wb = *(const int4*)(wp + 4);
        xp += 32; wp += 32;

        short8 a, b;
        a[0] = bf16_rne(xa.x); a[1] = bf16_rne(xa.y);
        a[2] = bf16_rne(xa.z); a[3] = bf16_rne(xa.w);
        a[4] = bf16_rne(xb.x); a[5] = bf16_rne(xb.y);
        a[6] = bf16_rne(xb.z); a[7] = bf16_rne(xb.w);

        b[0] = bf16_from_int(wa.x); b[1] = bf16_from_int(wa.y);
        b[2] = bf16_from_int(wa.z); b[3] = bf16_from_int(wa.w);
        b[4] = bf16_from_int(wb.x); b[5] = bf16_from_int(wb.y);
        b[6] = bf16_from_int(wb.z); b[7] = bf16_from_int(wb.w);

        acc = __builtin_amdgcn_mfma_f32_16x16x32_bf16(a, b, acc, 0, 0, 0);
    }

    // Cross-wave (K-segment) reduction in LDS, then fused scale+bias epilogue.
    __shared__ float red[WAVES][16][16];
    #pragma unroll
    for (int r = 0; r < 4; ++r)
        red[wave][g * 4 + r][m] = acc[r];   // row=(lane>>4)*4+r (token), col=lane&15 (output)
    __syncthreads();

    const int row = tid >> 4;   // token 0..15
    const int col = tid & 15;   // output within tile
    float s = red[0][row][col] + red[1][row][col]
            + red[2][row][col] + red[3][row][col];
    const int o = n0 + col;
    out[(size_t)row * OUT_F + o] = s * scale[o] + bias[o];
}

extern "C" void kernel_launch(void* const* d_in, const int* in_sizes, int n_in,
                              void* d_out, int out_size, void* d_ws, size_t ws_size,
                              hipStream_t stream) {
    const float* x     = (const float*)d_in[0];
    const int*   w     = (const int*)d_in[1];
    const float* scale = (const float*)d_in[2];
    const float* bias  = (const float*)d_in[3];
    float*       out   = (float*)d_out;

    Int8Linear_kernel<<<NTILES, 256, 0, stream>>>(x, w, scale, bias, out);
}